// Round 10
// baseline (70.194 us; speedup 1.0000x reference)
//
#include <hip/hip_runtime.h>

#define BOUNDING_PERC 0.05f

// ---------------------------------------------------------------------------
// init: inv[f] = -1  (4 MB of coalesced dword stores; avoids slow rocclr fill)
// ---------------------------------------------------------------------------
__global__ __launch_bounds__(256) void init_inv_kernel(
    int* __restrict__ inv, int n)
{
    int i = blockIdx.x * blockDim.x + threadIdx.x;
    if (i < n) inv[i] = -1;
}

// ---------------------------------------------------------------------------
// Prep: performs ALL ucenters gathers here (latency-tolerant small kernel)
//   vals[bb*nb + j] = { uc[bb][own[j]], uc[bb][nei[j]] }   (coalesced write)
//   inv[pos[j]] = j  (done once, by the bb==0 slice)
// This removes 4M random 64B-line fills from the big streaming kernel.
// ---------------------------------------------------------------------------
__global__ __launch_bounds__(256) void gather_vals_kernel(
    const int*   __restrict__ pos,
    const int*   __restrict__ own,
    const int*   __restrict__ nei,
    const float* __restrict__ uc,
    int*         __restrict__ inv,
    float2*      __restrict__ vals,
    int nb, int ncells, int nbatch)
{
    int idx = blockIdx.x * blockDim.x + threadIdx.x;
    if (idx >= nbatch * nb) return;
    int j  = idx % nb;
    int bb = idx / nb;
    const float* ucb = uc + (size_t)bb * ncells;
    float2 v;
    v.x = ucb[own[j]];
    v.y = ucb[nei[j]];
    vals[idx] = v;
    if (bb == 0) inv[pos[j]] = j;
}

// ---------------------------------------------------------------------------
// Fused streaming kernel (R9's proven body; gathers replaced by coalesced
// vals read). Barrier-free, wave-private LDS staging, cached loads.
// ---------------------------------------------------------------------------
__global__ __launch_bounds__(256) void fused_kernel(
    const float4* __restrict__ k4,     // (b*nfaces) float4's
    const float4* __restrict__ s4,     // (b*nfaces*9/4) float4's
    const float*  __restrict__ W,      // [4][9]
    const float*  __restrict__ bias,   // [9]
    const int*    __restrict__ inv,    // (nfaces), -1 = no fixup
    const float2* __restrict__ vals,   // (b*nb) {owner,neighbour} values
    float*        __restrict__ out,    // (b*nfaces)
    int nfaces, int nb)
{
    __shared__ float smem[2304];               // 4 waves * 576 floats
    const int tid  = threadIdx.x;
    const int wv   = tid >> 6;
    const int lane = tid & 63;
    float* mysm = smem + wv * 576;             // wave-private region

    const int gbase = blockIdx.x << 8;         // block face base
    const int gw    = gbase + (wv << 6);       // wave face base
    const int g     = gw + lane;               // global face index

    // ---- streaming burst (all coalesced, cached) ----
    const float4* sb  = s4 + ((size_t)gw * 9) / 4;   // gw*9 divisible by 4
    const float*  sbf = reinterpret_cast<const float*>(sb);
    float4 a0 = sb[lane];                      // source floats [0..255]
    float4 a1 = sb[lane + 64];                 // source floats [256..511]
    float  a2 = sbf[512 + lane];               // source floats [512..575]
    float4 kv = k4[g];

    const int bb = g / nfaces;                 // per-thread batch index
    const int f  = g - bb * nfaces;            // in-batch face index
    const int j  = inv[f];                     // coalesced dword

    // ---- stage into wave-private LDS ----
    float4* mysm4 = reinterpret_cast<float4*>(mysm);
    mysm4[lane]      = a0;
    mysm4[lane + 64] = a1;
    mysm[512 + lane] = a2;

    // ---- bounded-side values: coalesced float2 (no random gathers here) ----
    float o = 0.0f, n = 0.0f;
    if (j >= 0) {
        float2 v = vals[(size_t)bb * nb + j];
        o = v.x; n = v.y;
    }

    // ---- uniform weights -> SGPRs ----
    float Wr[4][9];
#pragma unroll
    for (int i = 0; i < 4; ++i)
#pragma unroll
        for (int s = 0; s < 9; ++s)
            Wr[i][s] = W[i * 9 + s];
    float br[9];
#pragma unroll
    for (int s = 0; s < 9; ++s) br[s] = bias[s];

    // ---- dot (stride-9 LDS reads: gcd(9,32)=1, conflict-free) ----
    const float* S = mysm + lane * 9;
    float acc = 0.0f;
#pragma unroll
    for (int s = 0; s < 9; ++s) {
        float c = br[s];
        c = fmaf(kv.x, Wr[0][s], c);
        c = fmaf(kv.y, Wr[1][s], c);
        c = fmaf(kv.z, Wr[2][s], c);
        c = fmaf(kv.w, Wr[3][s], c);
        acc = fmaf(c, S[s], acc);
    }

    float res = acc;
    if (j >= 0) {
        float smax = fmaxf(o, n), smin = fminf(o, n);
        float flux = 0.5f * (o + n);
        float up   = (flux >= 0.0f) ? o : n;
        float hi   = smax + BOUNDING_PERC * fabsf(smax);
        float lo   = smin - BOUNDING_PERC * fabsf(smin);
        bool valid = (acc >= lo) && (acc <= hi);
        res = valid ? acc : up;
    }
    out[g] = res;
}

// ---------------------------------------------------------------------------
// Fallback pass-1/pass-2 (used only if ws_size is too small)
// ---------------------------------------------------------------------------
__global__ __launch_bounds__(256) void ufaces_kernel(
    const float4* __restrict__ k4, const float4* __restrict__ s4,
    const float* __restrict__ W, const float* __restrict__ bias,
    float* __restrict__ out)
{
    __shared__ float s_src[2304];
    const int tid = threadIdx.x;
    const int base_face = blockIdx.x << 8;
    {
        const float4* src_blk = s4 + ((size_t)base_face * 9) / 4;
        float4* sm4 = reinterpret_cast<float4*>(s_src);
        sm4[tid]       = src_blk[tid];
        sm4[tid + 256] = src_blk[tid + 256];
        if (tid < 64) sm4[tid + 512] = src_blk[tid + 512];
    }
    float Wr[4][9];
#pragma unroll
    for (int i = 0; i < 4; ++i)
#pragma unroll
        for (int s = 0; s < 9; ++s) Wr[i][s] = W[i * 9 + s];
    float br[9];
#pragma unroll
    for (int s = 0; s < 9; ++s) br[s] = bias[s];
    const float4 kv = k4[base_face + tid];
    __syncthreads();
    const float* S = &s_src[tid * 9];
    float acc = 0.0f;
#pragma unroll
    for (int s = 0; s < 9; ++s) {
        float c = br[s];
        c = fmaf(kv.x, Wr[0][s], c);
        c = fmaf(kv.y, Wr[1][s], c);
        c = fmaf(kv.z, Wr[2][s], c);
        c = fmaf(kv.w, Wr[3][s], c);
        acc = fmaf(c, S[s], acc);
    }
    out[base_face + tid] = acc;
}

__global__ __launch_bounds__(256) void bound_kernel(
    const float* __restrict__ uc, const int* __restrict__ pos,
    const int* __restrict__ own, const int* __restrict__ nei,
    float* __restrict__ out, int nb, int nfaces, int ncells, int nbatch)
{
    int idx = blockIdx.x * blockDim.x + threadIdx.x;
    if (idx >= nbatch * nb) return;
    int j  = idx % nb;
    int bb = idx / nb;
    int p = pos[j];
    float uf = out[bb * nfaces + p];
    float o  = uc[bb * ncells + own[j]];
    float n  = uc[bb * ncells + nei[j]];
    float smax = fmaxf(o, n), smin = fminf(o, n);
    float flux = 0.5f * (o + n);
    float up   = (flux >= 0.0f) ? o : n;
    float hi   = smax + BOUNDING_PERC * fabsf(smax);
    float lo   = smin - BOUNDING_PERC * fabsf(smin);
    bool valid = (uf >= lo) && (uf <= hi);
    out[bb * nfaces + p] = valid ? uf : up;
}

extern "C" void kernel_launch(void* const* d_in, const int* in_sizes, int n_in,
                              void* d_out, int out_size, void* d_ws, size_t ws_size,
                              hipStream_t stream)
{
    const float* kernel_in  = (const float*)d_in[0];  // (b, nfaces, 4)
    const float* source     = (const float*)d_in[1];  // (b, nfaces, 3, 3)
    const float* ucenters   = (const float*)d_in[2];  // (b, ncells)
    const float* W          = (const float*)d_in[3];  // (4, 9)
    const float* bias       = (const float*)d_in[4];  // (9,)
    const int*   positions  = (const int*)d_in[5];    // (nb,)
    const int*   owners     = (const int*)d_in[6];    // (nb,)
    const int*   neighbours = (const int*)d_in[7];    // (nb,)
    float*       out        = (float*)d_out;          // (b, nfaces)

    const int b      = 4;
    const int in_dim = 4;
    const int nfaces = in_sizes[0] / (b * in_dim);
    const int ncells = in_sizes[2] / b;
    const int nb     = in_sizes[5];
    const int total_faces = b * nfaces;               // 4,000,000 (% 256 == 0)

    // workspace layout: inv (nfaces int) | vals (b*nb float2)
    const size_t need = (size_t)nfaces * sizeof(int) + (size_t)b * nb * sizeof(float2);
    if (ws_size >= need) {
        int*    inv  = (int*)d_ws;
        float2* vals = (float2*)(inv + nfaces);

        init_inv_kernel<<<(nfaces + 255) / 256, 256, 0, stream>>>(inv, nfaces);
        const int total_g = b * nb;
        gather_vals_kernel<<<(total_g + 255) / 256, 256, 0, stream>>>(
            positions, owners, neighbours, ucenters, inv, vals, nb, ncells, b);
        fused_kernel<<<total_faces / 256, 256, 0, stream>>>(
            (const float4*)kernel_in, (const float4*)source, W, bias,
            inv, vals, out, nfaces, nb);
    } else {
        ufaces_kernel<<<total_faces / 256, 256, 0, stream>>>(
            (const float4*)kernel_in, (const float4*)source, W, bias, out);
        int total = b * nb;
        bound_kernel<<<(total + 255) / 256, 256, 0, stream>>>(
            ucenters, positions, owners, neighbours, out, nb, nfaces, ncells, b);
    }
}

// Round 11
// 64.641 us; speedup vs baseline: 1.0859x; 1.0859x over previous
//
#include <hip/hip_runtime.h>

#define BOUNDING_PERC 0.05f

// ---------------------------------------------------------------------------
// init: mask words = 0  (1 MB coalesced dword stores; avoids rocclr fill)
// ---------------------------------------------------------------------------
__global__ __launch_bounds__(256) void init_mask_kernel(
    unsigned int* __restrict__ mask4, int nwords)
{
    int i = blockIdx.x * blockDim.x + threadIdx.x;
    if (i < nwords) mask4[i] = 0u;
}

// ---------------------------------------------------------------------------
// Prep: mask[pos[j]] = 1; own_f[pos[j]] = owners[j]; nei_f[pos[j]] = neighbours[j]
// own_f / nei_f need NO init: read only where mask != 0.
// ---------------------------------------------------------------------------
__global__ __launch_bounds__(256) void scatter_on_kernel(
    const int* __restrict__ pos, const int* __restrict__ own,
    const int* __restrict__ nei,
    int* __restrict__ own_f, int* __restrict__ nei_f,
    unsigned char* __restrict__ mask, int nb)
{
    int j = blockIdx.x * blockDim.x + threadIdx.x;
    if (j < nb) {
        int p = pos[j];
        own_f[p] = own[j];
        nei_f[p] = nei[j];
        mask[p]  = 1;
    }
}

// ---------------------------------------------------------------------------
// Fused kernel: R9 skeleton + (a) global_load_lds direct HBM->LDS staging of
// source (no VGPR round-trip), (b) 2 faces per thread (128-face wave window,
// ~7 KB in flight per wave). Barrier-free: each wave writes/reads ONLY its
// own LDS region. gl_lds issued FIRST so the compiler's counted vmcnt before
// the ds_reads can leave the uc gathers outstanding through the dot.
// ---------------------------------------------------------------------------
typedef __attribute__((address_space(1))) const void gas_t;
typedef __attribute__((address_space(3))) void las_t;

__global__ __launch_bounds__(256) void fused_kernel(
    const float4* __restrict__ k4,     // (b*nfaces) float4's
    const float4* __restrict__ s4,     // (b*nfaces*9/4) float4's
    const float*  __restrict__ W,      // [4][9]
    const float*  __restrict__ bias,   // [9]
    const unsigned char* __restrict__ mask, // (nfaces), 0 = no fixup
    const int*    __restrict__ own_f,  // (nfaces), valid where mask
    const int*    __restrict__ nei_f,  // (nfaces), valid where mask
    const float*  __restrict__ uc,     // (b*ncells)
    float*        __restrict__ out,    // (b*nfaces)
    int nfaces, int ncells, int total_faces)
{
    __shared__ float smem[4 * 1152];           // 4 waves * 128 faces * 9 f32
    const int tid  = threadIdx.x;
    const int wv   = tid >> 6;
    const int lane = tid & 63;
    float* mysm = smem + wv * 1152;            // wave-private region

    const int gw = (blockIdx.x << 9) + (wv << 7);   // wave face base
    if (gw >= total_faces) return;             // whole-wave tail guard

    // ---- source: direct HBM -> LDS (6 instrs cover 4608 B), issued FIRST --
    const float4* sb  = s4 + ((size_t)gw * 9) / 4;  // gw*9 % 4 == 0
    const float*  sbf = reinterpret_cast<const float*>(sb);
    float4* mysm4 = reinterpret_cast<float4*>(mysm);
#pragma unroll
    for (int k = 0; k < 4; ++k) {
        __builtin_amdgcn_global_load_lds(
            (gas_t*)(sb + k * 64 + lane), (las_t*)(mysm4 + k * 64), 16, 0, 0);
    }
#pragma unroll
    for (int t = 0; t < 2; ++t) {
        __builtin_amdgcn_global_load_lds(
            (gas_t*)(sbf + 1024 + t * 64 + lane), (las_t*)(mysm + 1024 + t * 64), 4, 0, 0);
    }

    // ---- per-face streaming loads (coalesced, cached) ----
    const int g0 = gw + lane;
    const int g1 = gw + 64 + lane;
    float4 kv0 = k4[g0];
    float4 kv1 = k4[g1];

    const int bb0 = g0 / nfaces;  const int f0 = g0 - bb0 * nfaces;
    const int bb1 = g1 / nfaces;  const int f1 = g1 - bb1 * nfaces;
    const bool lim0 = (mask[f0] != 0);         // coalesced byte loads
    const bool lim1 = (mask[f1] != 0);

    // ---- gated gathers issued early; latency hides under the dots ----
    float o0 = 0.0f, n0 = 0.0f, o1 = 0.0f, n1 = 0.0f;
    if (lim0) {
        const float* ucb = uc + (size_t)bb0 * ncells;
        o0 = ucb[own_f[f0]]; n0 = ucb[nei_f[f0]];
    }
    if (lim1) {
        const float* ucb = uc + (size_t)bb1 * ncells;
        o1 = ucb[own_f[f1]]; n1 = ucb[nei_f[f1]];
    }

    // ---- uniform weights -> SGPRs ----
    float Wr[4][9];
#pragma unroll
    for (int i = 0; i < 4; ++i)
#pragma unroll
        for (int s = 0; s < 9; ++s)
            Wr[i][s] = W[i * 9 + s];
    float br[9];
#pragma unroll
    for (int s = 0; s < 9; ++s) br[s] = bias[s];

    // ---- two dots (stride-9 LDS reads: gcd(9,32)=1, conflict-free) ----
    const float* S0 = mysm + lane * 9;
    const float* S1 = mysm + (64 + lane) * 9;
    float acc0 = 0.0f, acc1 = 0.0f;
#pragma unroll
    for (int s = 0; s < 9; ++s) {
        float c0 = br[s];
        c0 = fmaf(kv0.x, Wr[0][s], c0);
        c0 = fmaf(kv0.y, Wr[1][s], c0);
        c0 = fmaf(kv0.z, Wr[2][s], c0);
        c0 = fmaf(kv0.w, Wr[3][s], c0);
        acc0 = fmaf(c0, S0[s], acc0);
        float c1 = br[s];
        c1 = fmaf(kv1.x, Wr[0][s], c1);
        c1 = fmaf(kv1.y, Wr[1][s], c1);
        c1 = fmaf(kv1.z, Wr[2][s], c1);
        c1 = fmaf(kv1.w, Wr[3][s], c1);
        acc1 = fmaf(c1, S1[s], acc1);
    }

    // ---- bounded fixups ----
    float res0 = acc0;
    if (lim0) {
        float smax = fmaxf(o0, n0), smin = fminf(o0, n0);
        float flux = 0.5f * (o0 + n0);
        float up   = (flux >= 0.0f) ? o0 : n0;
        float hi   = smax + BOUNDING_PERC * fabsf(smax);
        float lo   = smin - BOUNDING_PERC * fabsf(smin);
        res0 = (acc0 >= lo && acc0 <= hi) ? acc0 : up;
    }
    float res1 = acc1;
    if (lim1) {
        float smax = fmaxf(o1, n1), smin = fminf(o1, n1);
        float flux = 0.5f * (o1 + n1);
        float up   = (flux >= 0.0f) ? o1 : n1;
        float hi   = smax + BOUNDING_PERC * fabsf(smax);
        float lo   = smin - BOUNDING_PERC * fabsf(smin);
        res1 = (acc1 >= lo && acc1 <= hi) ? acc1 : up;
    }
    out[g0] = res0;
    out[g1] = res1;
}

// ---------------------------------------------------------------------------
// Fallback pass-1/pass-2 (used only if ws_size is too small)
// ---------------------------------------------------------------------------
__global__ __launch_bounds__(256) void ufaces_kernel(
    const float4* __restrict__ k4, const float4* __restrict__ s4,
    const float* __restrict__ W, const float* __restrict__ bias,
    float* __restrict__ out)
{
    __shared__ float s_src[2304];
    const int tid = threadIdx.x;
    const int base_face = blockIdx.x << 8;
    {
        const float4* src_blk = s4 + ((size_t)base_face * 9) / 4;
        float4* sm4 = reinterpret_cast<float4*>(s_src);
        sm4[tid]       = src_blk[tid];
        sm4[tid + 256] = src_blk[tid + 256];
        if (tid < 64) sm4[tid + 512] = src_blk[tid + 512];
    }
    float Wr[4][9];
#pragma unroll
    for (int i = 0; i < 4; ++i)
#pragma unroll
        for (int s = 0; s < 9; ++s) Wr[i][s] = W[i * 9 + s];
    float br[9];
#pragma unroll
    for (int s = 0; s < 9; ++s) br[s] = bias[s];
    const float4 kv = k4[base_face + tid];
    __syncthreads();
    const float* S = &s_src[tid * 9];
    float acc = 0.0f;
#pragma unroll
    for (int s = 0; s < 9; ++s) {
        float c = br[s];
        c = fmaf(kv.x, Wr[0][s], c);
        c = fmaf(kv.y, Wr[1][s], c);
        c = fmaf(kv.z, Wr[2][s], c);
        c = fmaf(kv.w, Wr[3][s], c);
        acc = fmaf(c, S[s], acc);
    }
    out[base_face + tid] = acc;
}

__global__ __launch_bounds__(256) void bound_kernel(
    const float* __restrict__ uc, const int* __restrict__ pos,
    const int* __restrict__ own, const int* __restrict__ nei,
    float* __restrict__ out, int nb, int nfaces, int ncells, int nbatch)
{
    int idx = blockIdx.x * blockDim.x + threadIdx.x;
    if (idx >= nbatch * nb) return;
    int j  = idx % nb;
    int bb = idx / nb;
    int p = pos[j];
    float uf = out[bb * nfaces + p];
    float o  = uc[bb * ncells + own[j]];
    float n  = uc[bb * ncells + nei[j]];
    float smax = fmaxf(o, n), smin = fminf(o, n);
    float flux = 0.5f * (o + n);
    float up   = (flux >= 0.0f) ? o : n;
    float hi   = smax + BOUNDING_PERC * fabsf(smax);
    float lo   = smin - BOUNDING_PERC * fabsf(smin);
    bool valid = (uf >= lo) && (uf <= hi);
    out[bb * nfaces + p] = valid ? uf : up;
}

extern "C" void kernel_launch(void* const* d_in, const int* in_sizes, int n_in,
                              void* d_out, int out_size, void* d_ws, size_t ws_size,
                              hipStream_t stream)
{
    const float* kernel_in  = (const float*)d_in[0];  // (b, nfaces, 4)
    const float* source     = (const float*)d_in[1];  // (b, nfaces, 3, 3)
    const float* ucenters   = (const float*)d_in[2];  // (b, ncells)
    const float* W          = (const float*)d_in[3];  // (4, 9)
    const float* bias       = (const float*)d_in[4];  // (9,)
    const int*   positions  = (const int*)d_in[5];    // (nb,)
    const int*   owners     = (const int*)d_in[6];    // (nb,)
    const int*   neighbours = (const int*)d_in[7];    // (nb,)
    float*       out        = (float*)d_out;          // (b, nfaces)

    const int b      = 4;
    const int in_dim = 4;
    const int nfaces = in_sizes[0] / (b * in_dim);
    const int ncells = in_sizes[2] / b;
    const int nb     = in_sizes[5];
    const int total_faces = b * nfaces;               // 4,000,000 (% 128 == 0)

    // workspace layout: own_f (nfaces int) | nei_f (nfaces int) | mask (nfaces B)
    const size_t need = 2 * (size_t)nfaces * sizeof(int) + (size_t)nfaces;
    if (ws_size >= need) {
        int* own_f = (int*)d_ws;
        int* nei_f = own_f + nfaces;
        unsigned char* mask = (unsigned char*)(nei_f + nfaces);

        const int nwords = nfaces / 4;         // 1e6 % 4 == 0
        init_mask_kernel<<<(nwords + 255) / 256, 256, 0, stream>>>(
            (unsigned int*)mask, nwords);
        scatter_on_kernel<<<(nb + 255) / 256, 256, 0, stream>>>(
            positions, owners, neighbours, own_f, nei_f, mask, nb);

        const int faces_per_block = 512;       // 2 faces/thread
        const int grid = (total_faces + faces_per_block - 1) / faces_per_block;
        fused_kernel<<<grid, 256, 0, stream>>>(
            (const float4*)kernel_in, (const float4*)source, W, bias,
            mask, own_f, nei_f, ucenters, out, nfaces, ncells, total_faces);
    } else {
        ufaces_kernel<<<total_faces / 256, 256, 0, stream>>>(
            (const float4*)kernel_in, (const float4*)source, W, bias, out);
        int total = b * nb;
        bound_kernel<<<(total + 255) / 256, 256, 0, stream>>>(
            ucenters, positions, owners, neighbours, out, nb, nfaces, ncells, b);
    }
}